// Round 11
// baseline (1328.776 us; speedup 1.0000x reference)
//
#include <hip/hip_runtime.h>
#include <math.h>

#define BN_EPS 1e-5f
#define NBUK 32
typedef unsigned short u16;
typedef __attribute__((ext_vector_type(8))) short bf16x8;
typedef __attribute__((ext_vector_type(4))) float f32x4;

// ---------- bf16 helpers ----------
__device__ inline unsigned bfpack2(float a, float b){
  unsigned ua = __float_as_uint(a); ua = (ua + 0x7fffu + ((ua >> 16) & 1u)) >> 16;
  unsigned ub = __float_as_uint(b); ub = (ub + 0x7fffu + ((ub >> 16) & 1u)) >> 16;
  return ua | (ub << 16);
}
__device__ inline u16 bf16of(float a){
  unsigned ua = __float_as_uint(a); return (u16)((ua + 0x7fffu + ((ua >> 16) & 1u)) >> 16);
}
__device__ inline float bflo(unsigned u){ return __uint_as_float(u << 16); }
__device__ inline float bfhi(unsigned u){ return __uint_as_float(u & 0xffff0000u); }

// ---------------- preprocessing: CSR by dst (padded to 8-aligned per node) ----------------
// XCD-aware: chunk = blockIdx&7 -> all blocks of chunk c land on XCD c (round-robin dispatch),
// so deg/csr lines for that dst range stay in ONE XCD's L2.
// Also records rank[e] so k_fill needs no atomic.
__global__ void k_count(const int* __restrict__ ei, int E, int N, int* __restrict__ deg,
                        int* __restrict__ rank){
  int chunk = blockIdx.x & 7;
  int e = (blockIdx.x >> 3)*256 + threadIdx.x;
  int ET = E + N;
  if (e >= ET) return;
  int csz = (N + 7) >> 3;
  int lo = chunk*csz, hi = lo + csz; if (hi > N) hi = N;
  int dst = (e < E) ? ei[E + e] : (e - E);
  if (dst < lo || dst >= hi) return;
  rank[e] = atomicAdd(&deg[dst], 1);
}

// scan PADDED degrees (8-aligned) -- wave-shfl scan, 2 barriers
__global__ __launch_bounds__(1024) void k_scan_block(const int* __restrict__ deg, int* __restrict__ offs,
                                                     int* __restrict__ part, int N){
  int t = threadIdx.x; int i = blockIdx.x*1024 + t;
  int v = (i < N) ? ((deg[i] + 7) & ~7) : 0;
  int lane = t & 63, wid = t >> 6;
  int s = v;
  #pragma unroll
  for (int d = 1; d < 64; d <<= 1){
    int u = __shfl_up(s, d, 64);
    if (lane >= d) s += u;
  }
  __shared__ int wsum[16];
  if (lane == 63) wsum[wid] = s;
  __syncthreads();
  if (t < 16){
    int ws = wsum[t];
    #pragma unroll
    for (int d = 1; d < 16; d <<= 1){
      int u = __shfl_up(ws, d, 16);
      if (t >= d) ws += u;
    }
    wsum[t] = ws;   // inclusive wave sums
  }
  __syncthreads();
  int base = (wid > 0) ? wsum[wid - 1] : 0;
  if (i < N) offs[i] = base + s - v;          // exclusive
  if (t == 1023) part[blockIdx.x] = base + s; // block total
}

// exclusive scan of block partials (nb <= 1024) -- one block, wave-shfl
__global__ __launch_bounds__(1024) void k_scan_part(int* __restrict__ part, int nb){
  int t = threadIdx.x;
  int v = (t < nb) ? part[t] : 0;
  int lane = t & 63, wid = t >> 6;
  int s = v;
  #pragma unroll
  for (int d = 1; d < 64; d <<= 1){
    int u = __shfl_up(s, d, 64);
    if (lane >= d) s += u;
  }
  __shared__ int wsum[16];
  if (lane == 63) wsum[wid] = s;
  __syncthreads();
  if (t < 16){
    int ws = wsum[t];
    #pragma unroll
    for (int d = 1; d < 16; d <<= 1){
      int u = __shfl_up(ws, d, 16);
      if (t >= d) ws += u;
    }
    wsum[t] = ws;
  }
  __syncthreads();
  int base = (wid > 0) ? wsum[wid - 1] : 0;
  if (t < nb) part[t] = base + s - v;
}

// finalize offs AND fill the pad slots [offs+deg, offs+degp) with src=N (zero row)
__global__ void k_add_part(int* __restrict__ offs, const int* __restrict__ part,
                           const int* __restrict__ deg, int* __restrict__ csr, int N){
  int i = blockIdx.x*256 + threadIdx.x;
  if (i >= N) return;
  int o = offs[i] + part[i >> 10];
  offs[i] = o;
  int d = deg[i];
  int dp = (d + 7) & ~7;
  for (int j = d; j < dp; ++j) csr[o + j] = N;
}

// XCD-aware dst-chunk binding; no atomic (rank precomputed)
__global__ void k_fill(const int* __restrict__ ei, int E, int N, const int* __restrict__ offs,
                       const int* __restrict__ rank, int* __restrict__ csr){
  int chunk = blockIdx.x & 7;
  int e = (blockIdx.x >> 3)*256 + threadIdx.x;
  int ET = E + N;
  if (e >= ET) return;
  int csz = (N + 7) >> 3;
  int lo = chunk*csz, hi = lo + csz; if (hi > N) hi = N;
  int src, dst;
  if (e < E){
    dst = ei[E + e];
    if (dst < lo || dst >= hi) return;
    src = ei[e];
  } else {
    src = e - E; dst = src;
    if (dst < lo || dst >= hi) return;
  }
  csr[offs[dst] + rank[e]] = src;
}

// ---------------- degree-bucket permutation (uniform work per wave in agg kernels) ----------------
__global__ void k_hist(const int* __restrict__ deg, int* __restrict__ bhist, int N){
  __shared__ int h[NBUK];
  if (threadIdx.x < NBUK) h[threadIdx.x] = 0;
  __syncthreads();
  int i = blockIdx.x*256 + threadIdx.x;
  if (i < N){
    int dp = (deg[i] + 7) >> 3;
    int b = dp < NBUK ? dp : NBUK - 1;
    atomicAdd(&h[b], 1);
  }
  __syncthreads();
  if (threadIdx.x < NBUK && h[threadIdx.x]) atomicAdd(&bhist[threadIdx.x], h[threadIdx.x]);
}

__global__ void k_bucketscan(const int* __restrict__ bhist, int* __restrict__ boff,
                             int* __restrict__ bcur){
  int t = threadIdx.x;   // 0..31
  int v = bhist[t];
  int s = v;
  #pragma unroll
  for (int d = 1; d < 32; d <<= 1){
    int u = __shfl_up(s, d, 32);
    if (t >= d) s += u;
  }
  boff[t] = s - v;
  bcur[t] = 0;
}

__global__ void k_permfill(const int* __restrict__ deg, const int* __restrict__ boff,
                           int* __restrict__ bcur, int* __restrict__ perm, int N){
  int i = blockIdx.x*256 + threadIdx.x;
  if (i >= N) return;
  int dp = (deg[i] + 7) >> 3;
  int b = dp < NBUK ? dp : NBUK - 1;
  int pos = atomicAdd(&bcur[b], 1);
  perm[boff[b] + pos] = i;
}

// ---------------- weight convert (all 4 layers in one launch): WbT[n][k] = bf16(W[k][n]) ----------------
__global__ void k_wconv4(const float* __restrict__ W0, const float* __restrict__ W1,
                         const float* __restrict__ W2, const float* __restrict__ W3,
                         u16* __restrict__ WbT){
  int gid = blockIdx.x*256 + threadIdx.x;   // 65536
  int w = gid >> 14, id = gid & 16383;
  const float* W = (w == 0) ? W0 : (w == 1) ? W1 : (w == 2) ? W2 : W3;
  int nn = id >> 7, kk = id & 127;
  WbT[gid] = bf16of(W[kk*128 + nn]);
}

// ---------------- fold BN (eval) into scale/offset per layer: z = agg*dinv*S + T ----------------
__global__ void k_bnfold(const float* b1, const float* g1, const float* bb1, const float* m1, const float* v1,
                         const float* b2, const float* g2, const float* bb2, const float* m2, const float* v2,
                         const float* b3, const float* g3, const float* bb3, const float* m3, const float* v3,
                         float* __restrict__ S, float* __restrict__ T){
  int t = threadIdx.x;            // 0..383
  int layer = t >> 7, c = t & 127;
  const float *gb, *g, *bb, *m, *v;
  if (layer == 0){ gb=b1; g=g1; bb=bb1; m=m1; v=v1; }
  else if (layer == 1){ gb=b2; g=g2; bb=bb2; m=m2; v=v2; }
  else { gb=b3; g=g3; bb=bb3; m=m3; v=v3; }
  float s = g[c] * rsqrtf(v[c] + BN_EPS);
  S[t] = s;
  T[t] = (gb[c] - m[c]) * s + bb[c];
}

// ---------------- MFMA GEMM: Yb[M x 128](bf16) = bf16(A) @ WbT^T, row scale rsqrt(deg) ----------------
// 32 rows per wave (two 16-row fragment sets share each B-fragment load).
__global__ __launch_bounds__(256) void k_gemm_mfma(const float* __restrict__ Af,
                                                   const u16* __restrict__ Ab,
                                                   const u16* __restrict__ WbT,
                                                   u16* __restrict__ Yb, int M,
                                                   const int* __restrict__ deg){
  int lane = threadIdx.x & 63;
  int wv   = threadIdx.x >> 6;
  int row0 = blockIdx.x * 128 + wv * 32;
  int l15  = lane & 15;
  int g    = lane >> 4;
  int rA0  = row0 + l15;       if (rA0 >= M) rA0 = M - 1;
  int rA1  = row0 + 16 + l15;  if (rA1 >= M) rA1 = M - 1;

  bf16x8 afr0[4], afr1[4];
  if (Ab){
    const u16* ap0 = Ab + (size_t)rA0*128 + g*8;
    const u16* ap1 = Ab + (size_t)rA1*128 + g*8;
    #pragma unroll
    for (int s = 0; s < 4; ++s){
      afr0[s] = *(const bf16x8*)(ap0 + s*32);
      afr1[s] = *(const bf16x8*)(ap1 + s*32);
    }
  } else {
    const float* ap0 = Af + (size_t)rA0*128 + g*8;
    const float* ap1 = Af + (size_t)rA1*128 + g*8;
    #pragma unroll
    for (int s = 0; s < 4; ++s){
      float4 f0 = *(const float4*)(ap0 + s*32);
      float4 f1 = *(const float4*)(ap0 + s*32 + 4);
      union { bf16x8 v; unsigned u[4]; } t0;
      t0.u[0] = bfpack2(f0.x, f0.y); t0.u[1] = bfpack2(f0.z, f0.w);
      t0.u[2] = bfpack2(f1.x, f1.y); t0.u[3] = bfpack2(f1.z, f1.w);
      afr0[s] = t0.v;
      float4 f2 = *(const float4*)(ap1 + s*32);
      float4 f3 = *(const float4*)(ap1 + s*32 + 4);
      union { bf16x8 v; unsigned u[4]; } t1;
      t1.u[0] = bfpack2(f2.x, f2.y); t1.u[1] = bfpack2(f2.z, f2.w);
      t1.u[2] = bfpack2(f3.x, f3.y); t1.u[3] = bfpack2(f3.z, f3.w);
      afr1[s] = t1.v;
    }
  }

  f32x4 acc0[8] = {}, acc1[8] = {};
  #pragma unroll
  for (int s = 0; s < 4; ++s){
    union BU { uint4 q; bf16x8 v; } b[8];
    #pragma unroll
    for (int t = 0; t < 8; ++t){
      int col = t*16 + l15;
      b[t].q = ((const uint4*)(WbT + (size_t)col*128))[s*4 + g];
    }
    #pragma unroll
    for (int t = 0; t < 8; ++t){
      acc0[t] = __builtin_amdgcn_mfma_f32_16x16x32_bf16(afr0[s], b[t].v, acc0[t], 0, 0, 0);
      acc1[t] = __builtin_amdgcn_mfma_f32_16x16x32_bf16(afr1[s], b[t].v, acc1[t], 0, 0, 0);
    }
  }

  #pragma unroll
  for (int j = 0; j < 4; ++j){
    int r0 = row0 + g*4 + j;
    if (r0 < M){
      float sc = deg ? rsqrtf((float)deg[r0]) : 1.0f;
      #pragma unroll
      for (int t = 0; t < 8; ++t)
        Yb[(size_t)r0*128 + t*16 + l15] = bf16of(acc0[t][j] * sc);
    }
    int r1 = row0 + 16 + g*4 + j;
    if (r1 < M){
      float sc = deg ? rsqrtf((float)deg[r1]) : 1.0f;
      #pragma unroll
      for (int t = 0; t < 8; ++t)
        Yb[(size_t)r1*128 + t*16 + l15] = bf16of(acc1[t][j] * sc);
    }
  }
}

// ---------------- GAT: per-node attention logits ----------------
__global__ __launch_bounds__(256) void k_attn(const unsigned* __restrict__ Yb, const float* __restrict__ asrcw,
                                              const float* __restrict__ adstw,
                                              float* __restrict__ a_src, float* __restrict__ a_dst, int N){
  // init pad row: exp(leaky(-1e38 + adh)) == 0 for padded csr slots
  if (blockIdx.x == 0 && threadIdx.x < 4) a_src[(size_t)N*4 + threadIdx.x] = -1e38f;
  int n = (blockIdx.x*256 + threadIdx.x) >> 6;
  int lane = threadIdx.x & 63;
  if (n >= N) return;
  int head = lane >> 4;
  int d0 = (lane & 15) * 2;
  unsigned u = Yb[(size_t)n*64 + lane];
  float h0 = bflo(u), h1 = bfhi(u);
  float vs = h0 * asrcw[head*32 + d0] + h1 * asrcw[head*32 + d0 + 1];
  float vd = h0 * adstw[head*32 + d0] + h1 * adstw[head*32 + d0 + 1];
  #pragma unroll
  for (int m = 1; m < 16; m <<= 1){
    vs += __shfl_xor(vs, m, 64);
    vd += __shfl_xor(vd, m, 64);
  }
  if ((lane & 15) == 0){
    a_src[n*4 + head] = vs;
    a_dst[n*4 + head] = vd;
  }
}

// ---------------- GAT aggregation: fused edge weights, 16 lanes/node, 8-deep, perm order, bf16 out ----------------
__global__ __launch_bounds__(256) void k_gat_agg(const uint4* __restrict__ Yb4, const int* __restrict__ csr,
                                                 const int* __restrict__ offs, const int* __restrict__ deg,
                                                 const int* __restrict__ perm,
                                                 const float* __restrict__ asrc, const float* __restrict__ adst,
                                                 const float* __restrict__ bias, u16* __restrict__ outb, int N){
  int gid = blockIdx.x*16 + (threadIdx.x >> 4);
  int l = threadIdx.x & 15;            // 8 channels per lane
  if (gid >= N) return;
  int n = perm[gid];
  int head = l >> 2;
  int beg = offs[n], d = deg[n];
  int dp = (d + 7) & ~7;
  const uint4* cp4 = (const uint4*)(csr + beg);
  float adh = adst[n*4 + head];
  float a[8] = {};
  float sw = 0.f;
  uint4 ia = cp4[0], ib = cp4[1];
  for (int i = 0; i < dp; i += 8){
    int nx = (i + 8 < dp) ? ((i + 8) >> 2) : 0;
    uint4 na = cp4[nx], nb = cp4[nx + 1];
    uint4 v0 = Yb4[(size_t)ia.x*16 + l];
    uint4 v1 = Yb4[(size_t)ia.y*16 + l];
    uint4 v2 = Yb4[(size_t)ia.z*16 + l];
    uint4 v3 = Yb4[(size_t)ia.w*16 + l];
    uint4 v4 = Yb4[(size_t)ib.x*16 + l];
    uint4 v5 = Yb4[(size_t)ib.y*16 + l];
    uint4 v6 = Yb4[(size_t)ib.z*16 + l];
    uint4 v7 = Yb4[(size_t)ib.w*16 + l];
    float e0 = asrc[(size_t)ia.x*4 + head];
    float e1 = asrc[(size_t)ia.y*4 + head];
    float e2 = asrc[(size_t)ia.z*4 + head];
    float e3 = asrc[(size_t)ia.w*4 + head];
    float e4 = asrc[(size_t)ib.x*4 + head];
    float e5 = asrc[(size_t)ib.y*4 + head];
    float e6 = asrc[(size_t)ib.z*4 + head];
    float e7 = asrc[(size_t)ib.w*4 + head];
    float w[8];
    float ee[8] = {e0,e1,e2,e3,e4,e5,e6,e7};
    #pragma unroll
    for (int j = 0; j < 8; ++j){
      float e = ee[j] + adh; e = e > 0.f ? e : 0.2f*e;
      w[j] = __expf(e);
      sw += w[j];
    }
    uint4 vv[8] = {v0,v1,v2,v3,v4,v5,v6,v7};
    #pragma unroll
    for (int j = 0; j < 8; ++j){
      unsigned u0 = vv[j].x, u1 = vv[j].y, u2 = vv[j].z, u3 = vv[j].w;
      float wj = w[j];
      a[0] += wj*bflo(u0); a[1] += wj*bfhi(u0);
      a[2] += wj*bflo(u1); a[3] += wj*bfhi(u1);
      a[4] += wj*bflo(u2); a[5] += wj*bfhi(u2);
      a[6] += wj*bflo(u3); a[7] += wj*bfhi(u3);
    }
    ia = na; ib = nb;
  }
  float inv = 1.f / sw;
  int c0 = l*8;
  float4 b0 = *(const float4*)(bias + c0);
  float4 b1 = *(const float4*)(bias + c0 + 4);
  float bb8[8] = {b0.x,b0.y,b0.z,b0.w,b1.x,b1.y,b1.z,b1.w};
  float og[8];
  #pragma unroll
  for (int c = 0; c < 8; ++c){
    float z = a[c]*inv + bb8[c];
    og[c] = z > 0.f ? z : expm1f(z);
  }
  uint4 o;
  o.x = bfpack2(og[0], og[1]);
  o.y = bfpack2(og[2], og[3]);
  o.z = bfpack2(og[4], og[5]);
  o.w = bfpack2(og[6], og[7]);
  ((uint4*)(outb + (size_t)n*128))[l] = o;
}

// ---------------- GCN aggregation + folded BN + ELU + residual: 8-deep, perm order ----------------
__global__ __launch_bounds__(256) void k_gcn_agg(const uint4* __restrict__ Yb4, const u16* __restrict__ residb,
                                                 u16* __restrict__ outb, float* __restrict__ outf,
                                                 const int* __restrict__ csr,
                                                 const int* __restrict__ offs, const int* __restrict__ deg,
                                                 const int* __restrict__ perm,
                                                 const float* __restrict__ S, const float* __restrict__ T, int N){
  int gid = blockIdx.x*16 + (threadIdx.x >> 4);
  int l = threadIdx.x & 15;
  if (gid >= N) return;
  int n = perm[gid];
  int beg = offs[n], d = deg[n];
  int dp = (d + 7) & ~7;
  const uint4* cp4 = (const uint4*)(csr + beg);
  float a[8] = {};
  uint4 ia = cp4[0], ib = cp4[1];
  for (int i = 0; i < dp; i += 8){
    int nx = (i + 8 < dp) ? ((i + 8) >> 2) : 0;
    uint4 na = cp4[nx], nb = cp4[nx + 1];
    uint4 v0 = Yb4[(size_t)ia.x*16 + l];
    uint4 v1 = Yb4[(size_t)ia.y*16 + l];
    uint4 v2 = Yb4[(size_t)ia.z*16 + l];
    uint4 v3 = Yb4[(size_t)ia.w*16 + l];
    uint4 v4 = Yb4[(size_t)ib.x*16 + l];
    uint4 v5 = Yb4[(size_t)ib.y*16 + l];
    uint4 v6 = Yb4[(size_t)ib.z*16 + l];
    uint4 v7 = Yb4[(size_t)ib.w*16 + l];
    uint4 vv[8] = {v0,v1,v2,v3,v4,v5,v6,v7};
    #pragma unroll
    for (int j = 0; j < 8; ++j){
      unsigned u0 = vv[j].x, u1 = vv[j].y, u2 = vv[j].z, u3 = vv[j].w;
      a[0] += bflo(u0); a[1] += bfhi(u0);
      a[2] += bflo(u1); a[3] += bfhi(u1);
      a[4] += bflo(u2); a[5] += bfhi(u2);
      a[6] += bflo(u3); a[7] += bfhi(u3);
    }
    ia = na; ib = nb;
  }
  float dinv = rsqrtf((float)d);
  int c0 = l*8;
  float4 S0 = *(const float4*)(S + c0), S1 = *(const float4*)(S + c0 + 4);
  float4 T0 = *(const float4*)(T + c0), T1 = *(const float4*)(T + c0 + 4);
  float ss[8] = {S0.x,S0.y,S0.z,S0.w,S1.x,S1.y,S1.z,S1.w};
  float tt[8] = {T0.x,T0.y,T0.z,T0.w,T1.x,T1.y,T1.z,T1.w};
  float rr[8] = {};
  if (residb){
    uint4 r = ((const uint4*)(residb + (size_t)n*128))[l];
    rr[0]=bflo(r.x); rr[1]=bfhi(r.x); rr[2]=bflo(r.y); rr[3]=bfhi(r.y);
    rr[4]=bflo(r.z); rr[5]=bfhi(r.z); rr[6]=bflo(r.w); rr[7]=bfhi(r.w);
  }
  float og[8];
  #pragma unroll
  for (int c = 0; c < 8; ++c){
    float z = a[c]*dinv*ss[c] + tt[c];
    z = z > 0.f ? z : expm1f(z);
    og[c] = z + rr[c];
  }
  if (outb){
    uint4 o;
    o.x = bfpack2(og[0], og[1]);
    o.y = bfpack2(og[2], og[3]);
    o.z = bfpack2(og[4], og[5]);
    o.w = bfpack2(og[6], og[7]);
    ((uint4*)(outb + (size_t)n*128))[l] = o;
  } else {
    float* op = outf + (size_t)n*128 + c0;
    *(float4*)op       = make_float4(og[0],og[1],og[2],og[3]);
    *(float4*)(op + 4) = make_float4(og[4],og[5],og[6],og[7]);
  }
}

// ---------------- mean pool per graph (batch sorted) ----------------
__global__ __launch_bounds__(128) void k_pool(const float* __restrict__ H, const int* __restrict__ batch,
                                              float* __restrict__ G, int N){
  int gid = blockIdx.x; int c = threadIdx.x;
  int lo = 0, hi = N;
  while (lo < hi){ int mid = (lo + hi) >> 1; if (batch[mid] < gid) lo = mid + 1; else hi = mid; }
  int start = lo;
  lo = start; hi = N;
  while (lo < hi){ int mid = (lo + hi) >> 1; if (batch[mid] < gid + 1) lo = mid + 1; else hi = mid; }
  int end = lo;
  float acc = 0.f;
  for (int r = start; r < end; ++r) acc += H[(size_t)r*128 + c];
  float cnt = (float)(end - start);
  G[gid*128 + c] = acc / fmaxf(cnt, 1.0f);
}

// ---------------- MLP head ----------------
__global__ __launch_bounds__(128) void k_mlp(const float* __restrict__ G, const float* __restrict__ p1w,
                                             const float* __restrict__ p1b, const float* __restrict__ p2w,
                                             const float* __restrict__ p2b, const float* __restrict__ cw,
                                             const float* __restrict__ cb, float* __restrict__ out, int NG){
  int gid = blockIdx.x; int t = threadIdx.x;
  __shared__ float gv[128], t1[128], e[64];
  gv[t] = G[gid*128 + t];
  __syncthreads();
  float acc = p1b[t];
  for (int k = 0; k < 128; ++k) acc += gv[k] * p1w[k*128 + t];
  t1[t] = acc > 0.f ? acc : expm1f(acc);
  __syncthreads();
  if (t < 64){
    float a = p2b[t];
    for (int k = 0; k < 128; ++k) a += t1[k] * p2w[k*64 + t];
    e[t] = a;
    out[NG*3 + gid*64 + t] = a;
  }
  __syncthreads();
  if (t < 3){
    float a = cb[t];
    for (int k = 0; k < 64; ++k) a += e[k] * cw[k*3 + t];
    out[gid*3 + t] = a;
  }
}

extern "C" void kernel_launch(void* const* d_in, const int* in_sizes, int n_in,
                              void* d_out, int out_size, void* d_ws, size_t ws_size,
                              hipStream_t stream){
  const float* x      = (const float*)d_in[0];
  const int*   ei     = (const int*)d_in[1];
  const int*   batch  = (const int*)d_in[3];
  const float* gat_w  = (const float*)d_in[4];
  const float* att_s  = (const float*)d_in[5];
  const float* att_d  = (const float*)d_in[6];
  const float* gat_b  = (const float*)d_in[7];
  const float* w1 = (const float*)d_in[8];  const float* b1 = (const float*)d_in[9];
  const float* bn1g = (const float*)d_in[10], *bn1b = (const float*)d_in[11],
             * bn1m = (const float*)d_in[12], *bn1v = (const float*)d_in[13];
  const float* w2 = (const float*)d_in[14]; const float* b2 = (const float*)d_in[15];
  const float* bn2g = (const float*)d_in[16], *bn2b = (const float*)d_in[17],
             * bn2m = (const float*)d_in[18], *bn2v = (const float*)d_in[19];
  const float* w3 = (const float*)d_in[20]; const float* b3 = (const float*)d_in[21];
  const float* bn3g = (const float*)d_in[22], *bn3b = (const float*)d_in[23],
             * bn3m = (const float*)d_in[24], *bn3v = (const float*)d_in[25];
  const float* p1w = (const float*)d_in[26]; const float* p1b = (const float*)d_in[27];
  const float* p2w = (const float*)d_in[28]; const float* p2b = (const float*)d_in[29];
  const float* cw  = (const float*)d_in[30]; const float* cb  = (const float*)d_in[31];

  int N  = in_sizes[3];
  int E  = in_sizes[1] / 2;
  int ET = E + N;
  int NG = out_size / 67;

  char* ws = (char*)d_ws;
  size_t off = 0;
  auto alloc = [&](size_t bytes) -> void* {
    void* p = ws + off;
    off = (off + bytes + 255) & ~(size_t)255;
    return p;
  };
  u16*      Abf  = (u16*)alloc((size_t)N * 128 * 2);         // bf16 layer buffer
  u16*      Bbf  = (u16*)alloc((size_t)N * 128 * 2);         // bf16 layer buffer
  float*    Bact = (float*)alloc((size_t)N * 128 * 4);       // final (pool input) f32
  u16*      Yb   = (u16*)alloc((size_t)(N + 1) * 128 * 2);   // +1 zero pad row
  int*      csr  = (int*)alloc((size_t)(ET + 7*N) * 4);      // padded CSR (8-aligned)
  int*      rank = (int*)alloc((size_t)ET * 4);
  int*      deg  = (int*)alloc((size_t)N * 4);
  int*      offs = (int*)alloc((size_t)N * 4);
  int*      perm = (int*)alloc((size_t)N * 4);
  int*      part = (int*)alloc(1024 * 4);
  int*      bhist= (int*)alloc(NBUK * 4);
  int*      boff = (int*)alloc(NBUK * 4);
  int*      bcur = (int*)alloc(NBUK * 4);
  float*    asrc = (float*)alloc((size_t)(N + 1) * 4 * 4);   // +1 pad row = -1e38
  float*    adst = (float*)alloc((size_t)N * 4 * 4);
  float*    G    = (float*)alloc((size_t)NG * 128 * 4);
  u16*      Wb   = (u16*)alloc(65536 * 2);                   // 4 weight matrices
  float*    bnS  = (float*)alloc(384 * 4);
  float*    bnT  = (float*)alloc(384 * 4);

  hipMemsetAsync(deg,  0, (size_t)N * 4, stream);
  hipMemsetAsync(bhist, 0, NBUK * 4, stream);
  hipMemsetAsync(Yb + (size_t)N*128, 0, 256, stream);        // zero pad row

  int nb = (N + 1023) / 1024;
  int bpp = (ET + 255)/256;
  k_count<<<8*bpp, 256, 0, stream>>>(ei, E, N, deg, rank);
  k_scan_block<<<nb, 1024, 0, stream>>>(deg, offs, part, N);
  k_scan_part<<<1, 1024, 0, stream>>>(part, nb);
  k_hist<<<(N + 255)/256, 256, 0, stream>>>(deg, bhist, N);
  k_bucketscan<<<1, NBUK, 0, stream>>>(bhist, boff, bcur);
  k_add_part<<<(N + 255)/256, 256, 0, stream>>>(offs, part, deg, csr, N);
  k_permfill<<<(N + 255)/256, 256, 0, stream>>>(deg, boff, bcur, perm, N);
  k_fill<<<8*bpp, 256, 0, stream>>>(ei, E, N, offs, rank, csr);

  k_wconv4<<<256, 256, 0, stream>>>(gat_w, w1, w2, w3, Wb);
  k_bnfold<<<1, 384, 0, stream>>>(b1, bn1g, bn1b, bn1m, bn1v,
                                  b2, bn2g, bn2b, bn2m, bn2v,
                                  b3, bn3g, bn3b, bn3m, bn3v, bnS, bnT);

  int gblk = (N + 127) / 128;
  int nblk16 = (N + 15) / 16;
  int ablk = (N + 3) / 4;

  // GAT
  k_gemm_mfma<<<gblk, 256, 0, stream>>>(x, nullptr, Wb, Yb, N, nullptr);
  k_attn<<<ablk, 256, 0, stream>>>((const unsigned*)Yb, att_s, att_d, asrc, adst, N);
  k_gat_agg<<<nblk16, 256, 0, stream>>>((const uint4*)Yb, csr, offs, deg, perm, asrc, adst, gat_b, Abf, N);

  // GCN 1 (residual Abf), out Bbf (bf16)
  k_gemm_mfma<<<gblk, 256, 0, stream>>>(nullptr, Abf, Wb + 16384, Yb, N, deg);
  k_gcn_agg<<<nblk16, 256, 0, stream>>>((const uint4*)Yb, Abf, Bbf, nullptr, csr, offs, deg, perm, bnS, bnT, N);
  // GCN 2 (residual Bbf), out Abf (bf16)
  k_gemm_mfma<<<gblk, 256, 0, stream>>>(nullptr, Bbf, Wb + 32768, Yb, N, deg);
  k_gcn_agg<<<nblk16, 256, 0, stream>>>((const uint4*)Yb, Bbf, Abf, nullptr, csr, offs, deg, perm, bnS + 128, bnT + 128, N);
  // GCN 3 (no residual), out Bact (f32, feeds pool)
  k_gemm_mfma<<<gblk, 256, 0, stream>>>(nullptr, Abf, Wb + 49152, Yb, N, deg);
  k_gcn_agg<<<nblk16, 256, 0, stream>>>((const uint4*)Yb, nullptr, nullptr, Bact, csr, offs, deg, perm, bnS + 256, bnT + 256, N);

  // pool + head
  k_pool<<<NG, 128, 0, stream>>>(Bact, batch, G, N);
  k_mlp<<<NG, 128, 0, stream>>>(G, p1w, p1b, p2w, p2b, cw, cb, (float*)d_out, NG);
}

// Round 12
// 578.364 us; speedup vs baseline: 2.2975x; 2.2975x over previous
//
#include <hip/hip_runtime.h>
#include <math.h>

#define BN_EPS 1e-5f
#define NBUK 32
typedef unsigned short u16;
typedef __attribute__((ext_vector_type(8))) short bf16x8;
typedef __attribute__((ext_vector_type(4))) float f32x4;

// ---------- bf16 helpers ----------
__device__ inline unsigned bfpack2(float a, float b){
  unsigned ua = __float_as_uint(a); ua = (ua + 0x7fffu + ((ua >> 16) & 1u)) >> 16;
  unsigned ub = __float_as_uint(b); ub = (ub + 0x7fffu + ((ub >> 16) & 1u)) >> 16;
  return ua | (ub << 16);
}
__device__ inline u16 bf16of(float a){
  unsigned ua = __float_as_uint(a); return (u16)((ua + 0x7fffu + ((ua >> 16) & 1u)) >> 16);
}
__device__ inline float bflo(unsigned u){ return __uint_as_float(u << 16); }
__device__ inline float bfhi(unsigned u){ return __uint_as_float(u & 0xffff0000u); }

// ---------------- preprocessing: CSR by dst (padded to 8-aligned per node) ----------------
// XCD-aware: chunk = blockIdx&7 -> all blocks of chunk c land on XCD c (round-robin dispatch),
// so deg/csr lines for that dst range stay in ONE XCD's L2.
// Also records rank[e] so k_fill needs no atomic.
__global__ void k_count(const int* __restrict__ ei, int E, int N, int* __restrict__ deg,
                        int* __restrict__ rank){
  int chunk = blockIdx.x & 7;
  int e = (blockIdx.x >> 3)*256 + threadIdx.x;
  int ET = E + N;
  if (e >= ET) return;
  int csz = (N + 7) >> 3;
  int lo = chunk*csz, hi = lo + csz; if (hi > N) hi = N;
  int dst = (e < E) ? ei[E + e] : (e - E);
  if (dst < lo || dst >= hi) return;
  rank[e] = atomicAdd(&deg[dst], 1);
}

// scan PADDED degrees (8-aligned) -- wave-shfl scan, 2 barriers
__global__ __launch_bounds__(1024) void k_scan_block(const int* __restrict__ deg, int* __restrict__ offs,
                                                     int* __restrict__ part, int N){
  int t = threadIdx.x; int i = blockIdx.x*1024 + t;
  int v = (i < N) ? ((deg[i] + 7) & ~7) : 0;
  int lane = t & 63, wid = t >> 6;
  int s = v;
  #pragma unroll
  for (int d = 1; d < 64; d <<= 1){
    int u = __shfl_up(s, d, 64);
    if (lane >= d) s += u;
  }
  __shared__ int wsum[16];
  if (lane == 63) wsum[wid] = s;
  __syncthreads();
  if (t < 16){
    int ws = wsum[t];
    #pragma unroll
    for (int d = 1; d < 16; d <<= 1){
      int u = __shfl_up(ws, d, 16);
      if (t >= d) ws += u;
    }
    wsum[t] = ws;   // inclusive wave sums
  }
  __syncthreads();
  int base = (wid > 0) ? wsum[wid - 1] : 0;
  if (i < N) offs[i] = base + s - v;          // exclusive
  if (t == 1023) part[blockIdx.x] = base + s; // block total
}

// exclusive scan of block partials (nb <= 1024) -- one block, wave-shfl
__global__ __launch_bounds__(1024) void k_scan_part(int* __restrict__ part, int nb){
  int t = threadIdx.x;
  int v = (t < nb) ? part[t] : 0;
  int lane = t & 63, wid = t >> 6;
  int s = v;
  #pragma unroll
  for (int d = 1; d < 64; d <<= 1){
    int u = __shfl_up(s, d, 64);
    if (lane >= d) s += u;
  }
  __shared__ int wsum[16];
  if (lane == 63) wsum[wid] = s;
  __syncthreads();
  if (t < 16){
    int ws = wsum[t];
    #pragma unroll
    for (int d = 1; d < 16; d <<= 1){
      int u = __shfl_up(ws, d, 16);
      if (t >= d) ws += u;
    }
    wsum[t] = ws;
  }
  __syncthreads();
  int base = (wid > 0) ? wsum[wid - 1] : 0;
  if (t < nb) part[t] = base + s - v;
}

// finalize offs AND fill the pad slots [offs+deg, offs+degp) with src=N (zero row)
__global__ void k_add_part(int* __restrict__ offs, const int* __restrict__ part,
                           const int* __restrict__ deg, int* __restrict__ csr, int N){
  int i = blockIdx.x*256 + threadIdx.x;
  if (i >= N) return;
  int o = offs[i] + part[i >> 10];
  offs[i] = o;
  int d = deg[i];
  int dp = (d + 7) & ~7;
  for (int j = d; j < dp; ++j) csr[o + j] = N;
}

// XCD-aware dst-chunk binding; no atomic (rank precomputed)
__global__ void k_fill(const int* __restrict__ ei, int E, int N, const int* __restrict__ offs,
                       const int* __restrict__ rank, int* __restrict__ csr){
  int chunk = blockIdx.x & 7;
  int e = (blockIdx.x >> 3)*256 + threadIdx.x;
  int ET = E + N;
  if (e >= ET) return;
  int csz = (N + 7) >> 3;
  int lo = chunk*csz, hi = lo + csz; if (hi > N) hi = N;
  int src, dst;
  if (e < E){
    dst = ei[E + e];
    if (dst < lo || dst >= hi) return;
    src = ei[e];
  } else {
    src = e - E; dst = src;
    if (dst < lo || dst >= hi) return;
  }
  csr[offs[dst] + rank[e]] = src;
}

// ---------------- degree-bucket permutation: counting sort, NO global atomics ----------------
// Pass 1: per-block histogram -> gh[block][NBUK]
__global__ void k_hist_blk(const int* __restrict__ deg, int* __restrict__ gh, int N){
  __shared__ int h[NBUK];
  int t = threadIdx.x;
  if (t < NBUK) h[t] = 0;
  __syncthreads();
  int i = blockIdx.x*256 + t;
  if (i < N){
    int dp = (deg[i] + 7) >> 3;
    int b = dp < NBUK ? dp : NBUK - 1;
    atomicAdd(&h[b], 1);     // shared-memory atomic: cheap
  }
  __syncthreads();
  if (t < NBUK) gh[blockIdx.x*NBUK + t] = h[t];
}

// Pass 2: per-bucket column scan over blocks (32 blocks, one per bucket)
__global__ __launch_bounds__(1024) void k_colscan(int* __restrict__ gh, int* __restrict__ btot, int nbk){
  int b = blockIdx.x; int t = threadIdx.x;
  int v = (t < nbk) ? gh[t*NBUK + b] : 0;
  int lane = t & 63, wid = t >> 6;
  int s = v;
  #pragma unroll
  for (int d = 1; d < 64; d <<= 1){
    int u = __shfl_up(s, d, 64);
    if (lane >= d) s += u;
  }
  __shared__ int wsum[16];
  if (lane == 63) wsum[wid] = s;
  __syncthreads();
  if (t < 16){
    int ws = wsum[t];
    #pragma unroll
    for (int d = 1; d < 16; d <<= 1){
      int u = __shfl_up(ws, d, 16);
      if (t >= d) ws += u;
    }
    wsum[t] = ws;
  }
  __syncthreads();
  int base = (wid > 0) ? wsum[wid - 1] : 0;
  if (t < nbk) gh[t*NBUK + b] = base + s - v;     // exclusive prefix within bucket
  if (t == nbk - 1) btot[b] = base + s;           // bucket total
}

// Pass 3: exclusive scan of bucket totals
__global__ void k_bucketscan(const int* __restrict__ btot, int* __restrict__ boff){
  int t = threadIdx.x;   // 0..31
  int v = btot[t];
  int s = v;
  #pragma unroll
  for (int d = 1; d < 32; d <<= 1){
    int u = __shfl_up(s, d, 32);
    if (t >= d) s += u;
  }
  boff[t] = s - v;
}

// Pass 4: scatter perm (local rank via shared atomics; slot = boff + block prefix + rank)
__global__ void k_permfill(const int* __restrict__ deg, const int* __restrict__ boff,
                           const int* __restrict__ gh, int* __restrict__ perm, int N){
  __shared__ int h[NBUK];
  int t = threadIdx.x;
  if (t < NBUK) h[t] = 0;
  __syncthreads();
  int i = blockIdx.x*256 + t;
  int b = 0, r = 0;
  if (i < N){
    int dp = (deg[i] + 7) >> 3;
    b = dp < NBUK ? dp : NBUK - 1;
    r = atomicAdd(&h[b], 1);   // shared-memory atomic
    perm[boff[b] + gh[blockIdx.x*NBUK + b] + r] = i;
  }
}

// ---------------- weight convert (all 4 layers in one launch): WbT[n][k] = bf16(W[k][n]) ----------------
__global__ void k_wconv4(const float* __restrict__ W0, const float* __restrict__ W1,
                         const float* __restrict__ W2, const float* __restrict__ W3,
                         u16* __restrict__ WbT){
  int gid = blockIdx.x*256 + threadIdx.x;   // 65536
  int w = gid >> 14, id = gid & 16383;
  const float* W = (w == 0) ? W0 : (w == 1) ? W1 : (w == 2) ? W2 : W3;
  int nn = id >> 7, kk = id & 127;
  WbT[gid] = bf16of(W[kk*128 + nn]);
}

// ---------------- fold BN (eval) into scale/offset per layer: z = agg*dinv*S + T ----------------
__global__ void k_bnfold(const float* b1, const float* g1, const float* bb1, const float* m1, const float* v1,
                         const float* b2, const float* g2, const float* bb2, const float* m2, const float* v2,
                         const float* b3, const float* g3, const float* bb3, const float* m3, const float* v3,
                         float* __restrict__ S, float* __restrict__ T){
  int t = threadIdx.x;            // 0..383
  int layer = t >> 7, c = t & 127;
  const float *gb, *g, *bb, *m, *v;
  if (layer == 0){ gb=b1; g=g1; bb=bb1; m=m1; v=v1; }
  else if (layer == 1){ gb=b2; g=g2; bb=bb2; m=m2; v=v2; }
  else { gb=b3; g=g3; bb=bb3; m=m3; v=v3; }
  float s = g[c] * rsqrtf(v[c] + BN_EPS);
  S[t] = s;
  T[t] = (gb[c] - m[c]) * s + bb[c];
}

// ---------------- MFMA GEMM: Yb[M x 128](bf16) = bf16(A) @ WbT^T, row scale rsqrt(deg) ----------------
// 32 rows per wave (two 16-row fragment sets share each B-fragment load).
__global__ __launch_bounds__(256) void k_gemm_mfma(const float* __restrict__ Af,
                                                   const u16* __restrict__ Ab,
                                                   const u16* __restrict__ WbT,
                                                   u16* __restrict__ Yb, int M,
                                                   const int* __restrict__ deg){
  int lane = threadIdx.x & 63;
  int wv   = threadIdx.x >> 6;
  int row0 = blockIdx.x * 128 + wv * 32;
  int l15  = lane & 15;
  int g    = lane >> 4;
  int rA0  = row0 + l15;       if (rA0 >= M) rA0 = M - 1;
  int rA1  = row0 + 16 + l15;  if (rA1 >= M) rA1 = M - 1;

  bf16x8 afr0[4], afr1[4];
  if (Ab){
    const u16* ap0 = Ab + (size_t)rA0*128 + g*8;
    const u16* ap1 = Ab + (size_t)rA1*128 + g*8;
    #pragma unroll
    for (int s = 0; s < 4; ++s){
      afr0[s] = *(const bf16x8*)(ap0 + s*32);
      afr1[s] = *(const bf16x8*)(ap1 + s*32);
    }
  } else {
    const float* ap0 = Af + (size_t)rA0*128 + g*8;
    const float* ap1 = Af + (size_t)rA1*128 + g*8;
    #pragma unroll
    for (int s = 0; s < 4; ++s){
      float4 f0 = *(const float4*)(ap0 + s*32);
      float4 f1 = *(const float4*)(ap0 + s*32 + 4);
      union { bf16x8 v; unsigned u[4]; } t0;
      t0.u[0] = bfpack2(f0.x, f0.y); t0.u[1] = bfpack2(f0.z, f0.w);
      t0.u[2] = bfpack2(f1.x, f1.y); t0.u[3] = bfpack2(f1.z, f1.w);
      afr0[s] = t0.v;
      float4 f2 = *(const float4*)(ap1 + s*32);
      float4 f3 = *(const float4*)(ap1 + s*32 + 4);
      union { bf16x8 v; unsigned u[4]; } t1;
      t1.u[0] = bfpack2(f2.x, f2.y); t1.u[1] = bfpack2(f2.z, f2.w);
      t1.u[2] = bfpack2(f3.x, f3.y); t1.u[3] = bfpack2(f3.z, f3.w);
      afr1[s] = t1.v;
    }
  }

  f32x4 acc0[8] = {}, acc1[8] = {};
  #pragma unroll
  for (int s = 0; s < 4; ++s){
    union BU { uint4 q; bf16x8 v; } b[8];
    #pragma unroll
    for (int t = 0; t < 8; ++t){
      int col = t*16 + l15;
      b[t].q = ((const uint4*)(WbT + (size_t)col*128))[s*4 + g];
    }
    #pragma unroll
    for (int t = 0; t < 8; ++t){
      acc0[t] = __builtin_amdgcn_mfma_f32_16x16x32_bf16(afr0[s], b[t].v, acc0[t], 0, 0, 0);
      acc1[t] = __builtin_amdgcn_mfma_f32_16x16x32_bf16(afr1[s], b[t].v, acc1[t], 0, 0, 0);
    }
  }

  #pragma unroll
  for (int j = 0; j < 4; ++j){
    int r0 = row0 + g*4 + j;
    if (r0 < M){
      float sc = deg ? rsqrtf((float)deg[r0]) : 1.0f;
      #pragma unroll
      for (int t = 0; t < 8; ++t)
        Yb[(size_t)r0*128 + t*16 + l15] = bf16of(acc0[t][j] * sc);
    }
    int r1 = row0 + 16 + g*4 + j;
    if (r1 < M){
      float sc = deg ? rsqrtf((float)deg[r1]) : 1.0f;
      #pragma unroll
      for (int t = 0; t < 8; ++t)
        Yb[(size_t)r1*128 + t*16 + l15] = bf16of(acc1[t][j] * sc);
    }
  }
}

// ---------------- GAT: per-node attention logits ----------------
__global__ __launch_bounds__(256) void k_attn(const unsigned* __restrict__ Yb, const float* __restrict__ asrcw,
                                              const float* __restrict__ adstw,
                                              float* __restrict__ a_src, float* __restrict__ a_dst, int N){
  // init pad row: exp(leaky(-1e38 + adh)) == 0 for padded csr slots
  if (blockIdx.x == 0 && threadIdx.x < 4) a_src[(size_t)N*4 + threadIdx.x] = -1e38f;
  int n = (blockIdx.x*256 + threadIdx.x) >> 6;
  int lane = threadIdx.x & 63;
  if (n >= N) return;
  int head = lane >> 4;
  int d0 = (lane & 15) * 2;
  unsigned u = Yb[(size_t)n*64 + lane];
  float h0 = bflo(u), h1 = bfhi(u);
  float vs = h0 * asrcw[head*32 + d0] + h1 * asrcw[head*32 + d0 + 1];
  float vd = h0 * adstw[head*32 + d0] + h1 * adstw[head*32 + d0 + 1];
  #pragma unroll
  for (int m = 1; m < 16; m <<= 1){
    vs += __shfl_xor(vs, m, 64);
    vd += __shfl_xor(vd, m, 64);
  }
  if ((lane & 15) == 0){
    a_src[n*4 + head] = vs;
    a_dst[n*4 + head] = vd;
  }
}

// ---------------- GAT aggregation: fused edge weights, 16 lanes/node, 8-deep, perm order, bf16 out ----------------
__global__ __launch_bounds__(256) void k_gat_agg(const uint4* __restrict__ Yb4, const int* __restrict__ csr,
                                                 const int* __restrict__ offs, const int* __restrict__ deg,
                                                 const int* __restrict__ perm,
                                                 const float* __restrict__ asrc, const float* __restrict__ adst,
                                                 const float* __restrict__ bias, u16* __restrict__ outb, int N){
  int gid = blockIdx.x*16 + (threadIdx.x >> 4);
  int l = threadIdx.x & 15;            // 8 channels per lane
  if (gid >= N) return;
  int n = perm[gid];
  int head = l >> 2;
  int beg = offs[n], d = deg[n];
  int dp = (d + 7) & ~7;
  const uint4* cp4 = (const uint4*)(csr + beg);
  float adh = adst[n*4 + head];
  float a[8] = {};
  float sw = 0.f;
  uint4 ia = cp4[0], ib = cp4[1];
  for (int i = 0; i < dp; i += 8){
    int nx = (i + 8 < dp) ? ((i + 8) >> 2) : 0;
    uint4 na = cp4[nx], nb = cp4[nx + 1];
    uint4 v0 = Yb4[(size_t)ia.x*16 + l];
    uint4 v1 = Yb4[(size_t)ia.y*16 + l];
    uint4 v2 = Yb4[(size_t)ia.z*16 + l];
    uint4 v3 = Yb4[(size_t)ia.w*16 + l];
    uint4 v4 = Yb4[(size_t)ib.x*16 + l];
    uint4 v5 = Yb4[(size_t)ib.y*16 + l];
    uint4 v6 = Yb4[(size_t)ib.z*16 + l];
    uint4 v7 = Yb4[(size_t)ib.w*16 + l];
    float e0 = asrc[(size_t)ia.x*4 + head];
    float e1 = asrc[(size_t)ia.y*4 + head];
    float e2 = asrc[(size_t)ia.z*4 + head];
    float e3 = asrc[(size_t)ia.w*4 + head];
    float e4 = asrc[(size_t)ib.x*4 + head];
    float e5 = asrc[(size_t)ib.y*4 + head];
    float e6 = asrc[(size_t)ib.z*4 + head];
    float e7 = asrc[(size_t)ib.w*4 + head];
    float w[8];
    float ee[8] = {e0,e1,e2,e3,e4,e5,e6,e7};
    #pragma unroll
    for (int j = 0; j < 8; ++j){
      float e = ee[j] + adh; e = e > 0.f ? e : 0.2f*e;
      w[j] = __expf(e);
      sw += w[j];
    }
    uint4 vv[8] = {v0,v1,v2,v3,v4,v5,v6,v7};
    #pragma unroll
    for (int j = 0; j < 8; ++j){
      unsigned u0 = vv[j].x, u1 = vv[j].y, u2 = vv[j].z, u3 = vv[j].w;
      float wj = w[j];
      a[0] += wj*bflo(u0); a[1] += wj*bfhi(u0);
      a[2] += wj*bflo(u1); a[3] += wj*bfhi(u1);
      a[4] += wj*bflo(u2); a[5] += wj*bfhi(u2);
      a[6] += wj*bflo(u3); a[7] += wj*bfhi(u3);
    }
    ia = na; ib = nb;
  }
  float inv = 1.f / sw;
  int c0 = l*8;
  float4 b0 = *(const float4*)(bias + c0);
  float4 b1 = *(const float4*)(bias + c0 + 4);
  float bb8[8] = {b0.x,b0.y,b0.z,b0.w,b1.x,b1.y,b1.z,b1.w};
  float og[8];
  #pragma unroll
  for (int c = 0; c < 8; ++c){
    float z = a[c]*inv + bb8[c];
    og[c] = z > 0.f ? z : expm1f(z);
  }
  uint4 o;
  o.x = bfpack2(og[0], og[1]);
  o.y = bfpack2(og[2], og[3]);
  o.z = bfpack2(og[4], og[5]);
  o.w = bfpack2(og[6], og[7]);
  ((uint4*)(outb + (size_t)n*128))[l] = o;
}

// ---------------- GCN aggregation + folded BN + ELU + residual: 8-deep, perm order ----------------
__global__ __launch_bounds__(256) void k_gcn_agg(const uint4* __restrict__ Yb4, const u16* __restrict__ residb,
                                                 u16* __restrict__ outb, float* __restrict__ outf,
                                                 const int* __restrict__ csr,
                                                 const int* __restrict__ offs, const int* __restrict__ deg,
                                                 const int* __restrict__ perm,
                                                 const float* __restrict__ S, const float* __restrict__ T, int N){
  int gid = blockIdx.x*16 + (threadIdx.x >> 4);
  int l = threadIdx.x & 15;
  if (gid >= N) return;
  int n = perm[gid];
  int beg = offs[n], d = deg[n];
  int dp = (d + 7) & ~7;
  const uint4* cp4 = (const uint4*)(csr + beg);
  float a[8] = {};
  uint4 ia = cp4[0], ib = cp4[1];
  for (int i = 0; i < dp; i += 8){
    int nx = (i + 8 < dp) ? ((i + 8) >> 2) : 0;
    uint4 na = cp4[nx], nb = cp4[nx + 1];
    uint4 v0 = Yb4[(size_t)ia.x*16 + l];
    uint4 v1 = Yb4[(size_t)ia.y*16 + l];
    uint4 v2 = Yb4[(size_t)ia.z*16 + l];
    uint4 v3 = Yb4[(size_t)ia.w*16 + l];
    uint4 v4 = Yb4[(size_t)ib.x*16 + l];
    uint4 v5 = Yb4[(size_t)ib.y*16 + l];
    uint4 v6 = Yb4[(size_t)ib.z*16 + l];
    uint4 v7 = Yb4[(size_t)ib.w*16 + l];
    uint4 vv[8] = {v0,v1,v2,v3,v4,v5,v6,v7};
    #pragma unroll
    for (int j = 0; j < 8; ++j){
      unsigned u0 = vv[j].x, u1 = vv[j].y, u2 = vv[j].z, u3 = vv[j].w;
      a[0] += bflo(u0); a[1] += bfhi(u0);
      a[2] += bflo(u1); a[3] += bfhi(u1);
      a[4] += bflo(u2); a[5] += bfhi(u2);
      a[6] += bflo(u3); a[7] += bfhi(u3);
    }
    ia = na; ib = nb;
  }
  float dinv = rsqrtf((float)d);
  int c0 = l*8;
  float4 S0 = *(const float4*)(S + c0), S1 = *(const float4*)(S + c0 + 4);
  float4 T0 = *(const float4*)(T + c0), T1 = *(const float4*)(T + c0 + 4);
  float ss[8] = {S0.x,S0.y,S0.z,S0.w,S1.x,S1.y,S1.z,S1.w};
  float tt[8] = {T0.x,T0.y,T0.z,T0.w,T1.x,T1.y,T1.z,T1.w};
  float rr[8] = {};
  if (residb){
    uint4 r = ((const uint4*)(residb + (size_t)n*128))[l];
    rr[0]=bflo(r.x); rr[1]=bfhi(r.x); rr[2]=bflo(r.y); rr[3]=bfhi(r.y);
    rr[4]=bflo(r.z); rr[5]=bfhi(r.z); rr[6]=bflo(r.w); rr[7]=bfhi(r.w);
  }
  float og[8];
  #pragma unroll
  for (int c = 0; c < 8; ++c){
    float z = a[c]*dinv*ss[c] + tt[c];
    z = z > 0.f ? z : expm1f(z);
    og[c] = z + rr[c];
  }
  if (outb){
    uint4 o;
    o.x = bfpack2(og[0], og[1]);
    o.y = bfpack2(og[2], og[3]);
    o.z = bfpack2(og[4], og[5]);
    o.w = bfpack2(og[6], og[7]);
    ((uint4*)(outb + (size_t)n*128))[l] = o;
  } else {
    float* op = outf + (size_t)n*128 + c0;
    *(float4*)op       = make_float4(og[0],og[1],og[2],og[3]);
    *(float4*)(op + 4) = make_float4(og[4],og[5],og[6],og[7]);
  }
}

// ---------------- mean pool per graph (batch sorted) ----------------
__global__ __launch_bounds__(128) void k_pool(const float* __restrict__ H, const int* __restrict__ batch,
                                              float* __restrict__ G, int N){
  int gid = blockIdx.x; int c = threadIdx.x;
  int lo = 0, hi = N;
  while (lo < hi){ int mid = (lo + hi) >> 1; if (batch[mid] < gid) lo = mid + 1; else hi = mid; }
  int start = lo;
  lo = start; hi = N;
  while (lo < hi){ int mid = (lo + hi) >> 1; if (batch[mid] < gid + 1) lo = mid + 1; else hi = mid; }
  int end = lo;
  float acc = 0.f;
  for (int r = start; r < end; ++r) acc += H[(size_t)r*128 + c];
  float cnt = (float)(end - start);
  G[gid*128 + c] = acc / fmaxf(cnt, 1.0f);
}

// ---------------- MLP head ----------------
__global__ __launch_bounds__(128) void k_mlp(const float* __restrict__ G, const float* __restrict__ p1w,
                                             const float* __restrict__ p1b, const float* __restrict__ p2w,
                                             const float* __restrict__ p2b, const float* __restrict__ cw,
                                             const float* __restrict__ cb, float* __restrict__ out, int NG){
  int gid = blockIdx.x; int t = threadIdx.x;
  __shared__ float gv[128], t1[128], e[64];
  gv[t] = G[gid*128 + t];
  __syncthreads();
  float acc = p1b[t];
  for (int k = 0; k < 128; ++k) acc += gv[k] * p1w[k*128 + t];
  t1[t] = acc > 0.f ? acc : expm1f(acc);
  __syncthreads();
  if (t < 64){
    float a = p2b[t];
    for (int k = 0; k < 128; ++k) a += t1[k] * p2w[k*64 + t];
    e[t] = a;
    out[NG*3 + gid*64 + t] = a;
  }
  __syncthreads();
  if (t < 3){
    float a = cb[t];
    for (int k = 0; k < 64; ++k) a += e[k] * cw[k*3 + t];
    out[gid*3 + t] = a;
  }
}

extern "C" void kernel_launch(void* const* d_in, const int* in_sizes, int n_in,
                              void* d_out, int out_size, void* d_ws, size_t ws_size,
                              hipStream_t stream){
  const float* x      = (const float*)d_in[0];
  const int*   ei     = (const int*)d_in[1];
  const int*   batch  = (const int*)d_in[3];
  const float* gat_w  = (const float*)d_in[4];
  const float* att_s  = (const float*)d_in[5];
  const float* att_d  = (const float*)d_in[6];
  const float* gat_b  = (const float*)d_in[7];
  const float* w1 = (const float*)d_in[8];  const float* b1 = (const float*)d_in[9];
  const float* bn1g = (const float*)d_in[10], *bn1b = (const float*)d_in[11],
             * bn1m = (const float*)d_in[12], *bn1v = (const float*)d_in[13];
  const float* w2 = (const float*)d_in[14]; const float* b2 = (const float*)d_in[15];
  const float* bn2g = (const float*)d_in[16], *bn2b = (const float*)d_in[17],
             * bn2m = (const float*)d_in[18], *bn2v = (const float*)d_in[19];
  const float* w3 = (const float*)d_in[20]; const float* b3 = (const float*)d_in[21];
  const float* bn3g = (const float*)d_in[22], *bn3b = (const float*)d_in[23],
             * bn3m = (const float*)d_in[24], *bn3v = (const float*)d_in[25];
  const float* p1w = (const float*)d_in[26]; const float* p1b = (const float*)d_in[27];
  const float* p2w = (const float*)d_in[28]; const float* p2b = (const float*)d_in[29];
  const float* cw  = (const float*)d_in[30]; const float* cb  = (const float*)d_in[31];

  int N  = in_sizes[3];
  int E  = in_sizes[1] / 2;
  int ET = E + N;
  int NG = out_size / 67;

  char* ws = (char*)d_ws;
  size_t off = 0;
  auto alloc = [&](size_t bytes) -> void* {
    void* p = ws + off;
    off = (off + bytes + 255) & ~(size_t)255;
    return p;
  };
  u16*      Abf  = (u16*)alloc((size_t)N * 128 * 2);         // bf16 layer buffer
  u16*      Bbf  = (u16*)alloc((size_t)N * 128 * 2);         // bf16 layer buffer
  float*    Bact = (float*)alloc((size_t)N * 128 * 4);       // final (pool input) f32
  u16*      Yb   = (u16*)alloc((size_t)(N + 1) * 128 * 2);   // +1 zero pad row
  int*      csr  = (int*)alloc((size_t)(ET + 7*N) * 4);      // padded CSR (8-aligned)
  int*      rank = (int*)alloc((size_t)ET * 4);
  int*      deg  = (int*)alloc((size_t)N * 4);
  int*      offs = (int*)alloc((size_t)N * 4);
  int*      perm = (int*)alloc((size_t)N * 4);
  int*      part = (int*)alloc(1024 * 4);
  int       nb256 = (N + 255) / 256;
  int*      gh   = (int*)alloc((size_t)nb256 * NBUK * 4);
  int*      btot = (int*)alloc(NBUK * 4);
  int*      boff = (int*)alloc(NBUK * 4);
  float*    asrc = (float*)alloc((size_t)(N + 1) * 4 * 4);   // +1 pad row = -1e38
  float*    adst = (float*)alloc((size_t)N * 4 * 4);
  float*    G    = (float*)alloc((size_t)NG * 128 * 4);
  u16*      Wb   = (u16*)alloc(65536 * 2);                   // 4 weight matrices
  float*    bnS  = (float*)alloc(384 * 4);
  float*    bnT  = (float*)alloc(384 * 4);

  hipMemsetAsync(deg,  0, (size_t)N * 4, stream);
  hipMemsetAsync(Yb + (size_t)N*128, 0, 256, stream);        // zero pad row

  int nb = (N + 1023) / 1024;
  int bpp = (ET + 255)/256;
  k_count<<<8*bpp, 256, 0, stream>>>(ei, E, N, deg, rank);
  k_scan_block<<<nb, 1024, 0, stream>>>(deg, offs, part, N);
  k_scan_part<<<1, 1024, 0, stream>>>(part, nb);
  k_hist_blk<<<nb256, 256, 0, stream>>>(deg, gh, N);
  k_colscan<<<NBUK, 1024, 0, stream>>>(gh, btot, nb256);
  k_bucketscan<<<1, NBUK, 0, stream>>>(btot, boff);
  k_add_part<<<(N + 255)/256, 256, 0, stream>>>(offs, part, deg, csr, N);
  k_permfill<<<nb256, 256, 0, stream>>>(deg, boff, gh, perm, N);
  k_fill<<<8*bpp, 256, 0, stream>>>(ei, E, N, offs, rank, csr);

  k_wconv4<<<256, 256, 0, stream>>>(gat_w, w1, w2, w3, Wb);
  k_bnfold<<<1, 384, 0, stream>>>(b1, bn1g, bn1b, bn1m, bn1v,
                                  b2, bn2g, bn2b, bn2m, bn2v,
                                  b3, bn3g, bn3b, bn3m, bn3v, bnS, bnT);

  int gblk = (N + 127) / 128;
  int nblk16 = (N + 15) / 16;
  int ablk = (N + 3) / 4;

  // GAT
  k_gemm_mfma<<<gblk, 256, 0, stream>>>(x, nullptr, Wb, Yb, N, nullptr);
  k_attn<<<ablk, 256, 0, stream>>>((const unsigned*)Yb, att_s, att_d, asrc, adst, N);
  k_gat_agg<<<nblk16, 256, 0, stream>>>((const uint4*)Yb, csr, offs, deg, perm, asrc, adst, gat_b, Abf, N);

  // GCN 1 (residual Abf), out Bbf (bf16)
  k_gemm_mfma<<<gblk, 256, 0, stream>>>(nullptr, Abf, Wb + 16384, Yb, N, deg);
  k_gcn_agg<<<nblk16, 256, 0, stream>>>((const uint4*)Yb, Abf, Bbf, nullptr, csr, offs, deg, perm, bnS, bnT, N);
  // GCN 2 (residual Bbf), out Abf (bf16)
  k_gemm_mfma<<<gblk, 256, 0, stream>>>(nullptr, Bbf, Wb + 32768, Yb, N, deg);
  k_gcn_agg<<<nblk16, 256, 0, stream>>>((const uint4*)Yb, Bbf, Abf, nullptr, csr, offs, deg, perm, bnS + 128, bnT + 128, N);
  // GCN 3 (no residual), out Bact (f32, feeds pool)
  k_gemm_mfma<<<gblk, 256, 0, stream>>>(nullptr, Abf, Wb + 49152, Yb, N, deg);
  k_gcn_agg<<<nblk16, 256, 0, stream>>>((const uint4*)Yb, nullptr, nullptr, Bact, csr, offs, deg, perm, bnS + 256, bnT + 256, N);

  // pool + head
  k_pool<<<NG, 128, 0, stream>>>(Bact, batch, G, N);
  k_mlp<<<NG, 128, 0, stream>>>(G, p1w, p1b, p2w, p2b, cw, cb, (float*)d_out, NG);
}

// Round 13
// 576.316 us; speedup vs baseline: 2.3056x; 1.0036x over previous
//
#include <hip/hip_runtime.h>
#include <math.h>

#define BN_EPS 1e-5f
#define NBUK 32
typedef unsigned short u16;
typedef __attribute__((ext_vector_type(8))) short bf16x8;
typedef __attribute__((ext_vector_type(4))) float f32x4;

// ---------- bf16 helpers ----------
__device__ inline unsigned bfpack2(float a, float b){
  unsigned ua = __float_as_uint(a); ua = (ua + 0x7fffu + ((ua >> 16) & 1u)) >> 16;
  unsigned ub = __float_as_uint(b); ub = (ub + 0x7fffu + ((ub >> 16) & 1u)) >> 16;
  return ua | (ub << 16);
}
__device__ inline u16 bf16of(float a){
  unsigned ua = __float_as_uint(a); return (u16)((ua + 0x7fffu + ((ua >> 16) & 1u)) >> 16);
}
__device__ inline float bflo(unsigned u){ return __uint_as_float(u << 16); }
__device__ inline float bfhi(unsigned u){ return __uint_as_float(u & 0xffff0000u); }

// ---------------- preprocessing: CSR by dst (padded to 8-aligned per node) ----------------
// XCD-aware: chunk = blockIdx&7 -> all blocks of chunk c land on XCD c (round-robin dispatch),
// so deg/csr lines for that dst range stay in ONE XCD's L2.
// Also records rank[e] so k_fill needs no atomic.
__global__ void k_count(const int* __restrict__ ei, int E, int N, int* __restrict__ deg,
                        int* __restrict__ rank){
  int chunk = blockIdx.x & 7;
  int e = (blockIdx.x >> 3)*256 + threadIdx.x;
  int ET = E + N;
  if (e >= ET) return;
  int csz = (N + 7) >> 3;
  int lo = chunk*csz, hi = lo + csz; if (hi > N) hi = N;
  int dst = (e < E) ? ei[E + e] : (e - E);
  if (dst < lo || dst >= hi) return;
  rank[e] = atomicAdd(&deg[dst], 1);
}

// scan PADDED degrees (8-aligned) -- wave-shfl scan, 2 barriers
__global__ __launch_bounds__(1024) void k_scan_block(const int* __restrict__ deg, int* __restrict__ offs,
                                                     int* __restrict__ part, int N){
  int t = threadIdx.x; int i = blockIdx.x*1024 + t;
  int v = (i < N) ? ((deg[i] + 7) & ~7) : 0;
  int lane = t & 63, wid = t >> 6;
  int s = v;
  #pragma unroll
  for (int d = 1; d < 64; d <<= 1){
    int u = __shfl_up(s, d, 64);
    if (lane >= d) s += u;
  }
  __shared__ int wsum[16];
  if (lane == 63) wsum[wid] = s;
  __syncthreads();
  if (t < 16){
    int ws = wsum[t];
    #pragma unroll
    for (int d = 1; d < 16; d <<= 1){
      int u = __shfl_up(ws, d, 16);
      if (t >= d) ws += u;
    }
    wsum[t] = ws;   // inclusive wave sums
  }
  __syncthreads();
  int base = (wid > 0) ? wsum[wid - 1] : 0;
  if (i < N) offs[i] = base + s - v;          // exclusive
  if (t == 1023) part[blockIdx.x] = base + s; // block total
}

// exclusive scan of block partials (nb <= 1024) -- one block, wave-shfl
__global__ __launch_bounds__(1024) void k_scan_part(int* __restrict__ part, int nb){
  int t = threadIdx.x;
  int v = (t < nb) ? part[t] : 0;
  int lane = t & 63, wid = t >> 6;
  int s = v;
  #pragma unroll
  for (int d = 1; d < 64; d <<= 1){
    int u = __shfl_up(s, d, 64);
    if (lane >= d) s += u;
  }
  __shared__ int wsum[16];
  if (lane == 63) wsum[wid] = s;
  __syncthreads();
  if (t < 16){
    int ws = wsum[t];
    #pragma unroll
    for (int d = 1; d < 16; d <<= 1){
      int u = __shfl_up(ws, d, 16);
      if (t >= d) ws += u;
    }
    wsum[t] = ws;
  }
  __syncthreads();
  int base = (wid > 0) ? wsum[wid - 1] : 0;
  if (t < nb) part[t] = base + s - v;
}

// XCD-aware dst-chunk binding; no atomic (rank precomputed)
__global__ void k_fill(const int* __restrict__ ei, int E, int N, const int* __restrict__ offs,
                       const int* __restrict__ rank, int* __restrict__ csr){
  int chunk = blockIdx.x & 7;
  int e = (blockIdx.x >> 3)*256 + threadIdx.x;
  int ET = E + N;
  if (e >= ET) return;
  int csz = (N + 7) >> 3;
  int lo = chunk*csz, hi = lo + csz; if (hi > N) hi = N;
  int src, dst;
  if (e < E){
    dst = ei[E + e];
    if (dst < lo || dst >= hi) return;
    src = ei[e];
  } else {
    src = e - E; dst = src;
    if (dst < lo || dst >= hi) return;
  }
  csr[offs[dst] + rank[e]] = src;
}

// ---------------- degree-bucket permutation: counting sort, NO global atomics ----------------
// Pass 1: per-block histogram -> gh[block][NBUK]
__global__ void k_hist_blk(const int* __restrict__ deg, int* __restrict__ gh, int N){
  __shared__ int h[NBUK];
  int t = threadIdx.x;
  if (t < NBUK) h[t] = 0;
  __syncthreads();
  int i = blockIdx.x*256 + t;
  if (i < N){
    int dp = (deg[i] + 7) >> 3;
    int b = dp < NBUK ? dp : NBUK - 1;
    atomicAdd(&h[b], 1);     // shared-memory atomic: cheap
  }
  __syncthreads();
  if (t < NBUK) gh[blockIdx.x*NBUK + t] = h[t];
}

// Pass 2: per-bucket column scan over blocks (32 blocks, one per bucket)
__global__ __launch_bounds__(1024) void k_colscan(int* __restrict__ gh, int* __restrict__ btot, int nbk){
  int b = blockIdx.x; int t = threadIdx.x;
  int v = (t < nbk) ? gh[t*NBUK + b] : 0;
  int lane = t & 63, wid = t >> 6;
  int s = v;
  #pragma unroll
  for (int d = 1; d < 64; d <<= 1){
    int u = __shfl_up(s, d, 64);
    if (lane >= d) s += u;
  }
  __shared__ int wsum[16];
  if (lane == 63) wsum[wid] = s;
  __syncthreads();
  if (t < 16){
    int ws = wsum[t];
    #pragma unroll
    for (int d = 1; d < 16; d <<= 1){
      int u = __shfl_up(ws, d, 16);
      if (t >= d) ws += u;
    }
    wsum[t] = ws;
  }
  __syncthreads();
  int base = (wid > 0) ? wsum[wid - 1] : 0;
  if (t < nbk) gh[t*NBUK + b] = base + s - v;     // exclusive prefix within bucket
  if (t == nbk - 1) btot[b] = base + s;           // bucket total
}

// Pass 3: exclusive scan of bucket totals in DESCENDING-degree order (heavy buckets first:
// LPT scheduling -- heavy blocks launch at grid start, light blocks backfill the tail)
__global__ void k_bucketscan(const int* __restrict__ btot, int* __restrict__ boff){
  int t = threadIdx.x;   // 0..31
  int rb = NBUK - 1 - t; // reversed bucket index
  int v = btot[rb];
  int s = v;
  #pragma unroll
  for (int d = 1; d < 32; d <<= 1){
    int u = __shfl_up(s, d, 32);
    if (t >= d) s += u;
  }
  boff[rb] = s - v;
}

// Pass 4 (merged): finalize offs + pad csr slots + scatter perm
__global__ void k_finalize(int* __restrict__ offs, const int* __restrict__ part,
                           const int* __restrict__ deg, int* __restrict__ csr,
                           const int* __restrict__ boff, const int* __restrict__ gh,
                           int* __restrict__ perm, int N){
  __shared__ int h[NBUK];
  int t = threadIdx.x;
  if (t < NBUK) h[t] = 0;
  __syncthreads();
  int i = blockIdx.x*256 + t;
  if (i >= N) return;
  // finalize offs + pad
  int o = offs[i] + part[i >> 10];
  offs[i] = o;
  int d = deg[i];
  int dp = (d + 7) & ~7;
  for (int j = d; j < dp; ++j) csr[o + j] = N;
  // perm scatter (shared-mem local rank)
  int dpb = (d + 7) >> 3;
  int b = dpb < NBUK ? dpb : NBUK - 1;
  int r = atomicAdd(&h[b], 1);
  perm[boff[b] + gh[blockIdx.x*NBUK + b] + r] = i;
}

// ---------------- weight convert (all 4 layers in one launch): WbT[n][k] = bf16(W[k][n]) ----------------
__global__ void k_wconv4(const float* __restrict__ W0, const float* __restrict__ W1,
                         const float* __restrict__ W2, const float* __restrict__ W3,
                         u16* __restrict__ WbT){
  int gid = blockIdx.x*256 + threadIdx.x;   // 65536
  int w = gid >> 14, id = gid & 16383;
  const float* W = (w == 0) ? W0 : (w == 1) ? W1 : (w == 2) ? W2 : W3;
  int nn = id >> 7, kk = id & 127;
  WbT[gid] = bf16of(W[kk*128 + nn]);
}

// ---------------- fold BN (eval) into scale/offset per layer: z = agg*dinv*S + T ----------------
__global__ void k_bnfold(const float* b1, const float* g1, const float* bb1, const float* m1, const float* v1,
                         const float* b2, const float* g2, const float* bb2, const float* m2, const float* v2,
                         const float* b3, const float* g3, const float* bb3, const float* m3, const float* v3,
                         float* __restrict__ S, float* __restrict__ T){
  int t = threadIdx.x;            // 0..383
  int layer = t >> 7, c = t & 127;
  const float *gb, *g, *bb, *m, *v;
  if (layer == 0){ gb=b1; g=g1; bb=bb1; m=m1; v=v1; }
  else if (layer == 1){ gb=b2; g=g2; bb=bb2; m=m2; v=v2; }
  else { gb=b3; g=g3; bb=bb3; m=m3; v=v3; }
  float s = g[c] * rsqrtf(v[c] + BN_EPS);
  S[t] = s;
  T[t] = (gb[c] - m[c]) * s + bb[c];
}

// ---------------- MFMA GEMM: Yb[M x 128](bf16) = bf16(A) @ WbT^T, row scale rsqrt(deg) ----------------
// 32 rows per wave (two 16-row fragment sets share each B-fragment load).
__global__ __launch_bounds__(256) void k_gemm_mfma(const float* __restrict__ Af,
                                                   const u16* __restrict__ Ab,
                                                   const u16* __restrict__ WbT,
                                                   u16* __restrict__ Yb, int M,
                                                   const int* __restrict__ deg){
  int lane = threadIdx.x & 63;
  int wv   = threadIdx.x >> 6;
  int row0 = blockIdx.x * 128 + wv * 32;
  int l15  = lane & 15;
  int g    = lane >> 4;
  int rA0  = row0 + l15;       if (rA0 >= M) rA0 = M - 1;
  int rA1  = row0 + 16 + l15;  if (rA1 >= M) rA1 = M - 1;

  bf16x8 afr0[4], afr1[4];
  if (Ab){
    const u16* ap0 = Ab + (size_t)rA0*128 + g*8;
    const u16* ap1 = Ab + (size_t)rA1*128 + g*8;
    #pragma unroll
    for (int s = 0; s < 4; ++s){
      afr0[s] = *(const bf16x8*)(ap0 + s*32);
      afr1[s] = *(const bf16x8*)(ap1 + s*32);
    }
  } else {
    const float* ap0 = Af + (size_t)rA0*128 + g*8;
    const float* ap1 = Af + (size_t)rA1*128 + g*8;
    #pragma unroll
    for (int s = 0; s < 4; ++s){
      float4 f0 = *(const float4*)(ap0 + s*32);
      float4 f1 = *(const float4*)(ap0 + s*32 + 4);
      union { bf16x8 v; unsigned u[4]; } t0;
      t0.u[0] = bfpack2(f0.x, f0.y); t0.u[1] = bfpack2(f0.z, f0.w);
      t0.u[2] = bfpack2(f1.x, f1.y); t0.u[3] = bfpack2(f1.z, f1.w);
      afr0[s] = t0.v;
      float4 f2 = *(const float4*)(ap1 + s*32);
      float4 f3 = *(const float4*)(ap1 + s*32 + 4);
      union { bf16x8 v; unsigned u[4]; } t1;
      t1.u[0] = bfpack2(f2.x, f2.y); t1.u[1] = bfpack2(f2.z, f2.w);
      t1.u[2] = bfpack2(f3.x, f3.y); t1.u[3] = bfpack2(f3.z, f3.w);
      afr1[s] = t1.v;
    }
  }

  f32x4 acc0[8] = {}, acc1[8] = {};
  #pragma unroll
  for (int s = 0; s < 4; ++s){
    union BU { uint4 q; bf16x8 v; } b[8];
    #pragma unroll
    for (int t = 0; t < 8; ++t){
      int col = t*16 + l15;
      b[t].q = ((const uint4*)(WbT + (size_t)col*128))[s*4 + g];
    }
    #pragma unroll
    for (int t = 0; t < 8; ++t){
      acc0[t] = __builtin_amdgcn_mfma_f32_16x16x32_bf16(afr0[s], b[t].v, acc0[t], 0, 0, 0);
      acc1[t] = __builtin_amdgcn_mfma_f32_16x16x32_bf16(afr1[s], b[t].v, acc1[t], 0, 0, 0);
    }
  }

  #pragma unroll
  for (int j = 0; j < 4; ++j){
    int r0 = row0 + g*4 + j;
    if (r0 < M){
      float sc = deg ? rsqrtf((float)deg[r0]) : 1.0f;
      #pragma unroll
      for (int t = 0; t < 8; ++t)
        Yb[(size_t)r0*128 + t*16 + l15] = bf16of(acc0[t][j] * sc);
    }
    int r1 = row0 + 16 + g*4 + j;
    if (r1 < M){
      float sc = deg ? rsqrtf((float)deg[r1]) : 1.0f;
      #pragma unroll
      for (int t = 0; t < 8; ++t)
        Yb[(size_t)r1*128 + t*16 + l15] = bf16of(acc1[t][j] * sc);
    }
  }
}

// ---------------- GAT: per-node attention logits ----------------
__global__ __launch_bounds__(256) void k_attn(const unsigned* __restrict__ Yb, const float* __restrict__ asrcw,
                                              const float* __restrict__ adstw,
                                              float* __restrict__ a_src, float* __restrict__ a_dst, int N){
  // init pad row: exp(leaky(-1e38 + adh)) == 0 for padded csr slots
  if (blockIdx.x == 0 && threadIdx.x < 4) a_src[(size_t)N*4 + threadIdx.x] = -1e38f;
  int n = (blockIdx.x*256 + threadIdx.x) >> 6;
  int lane = threadIdx.x & 63;
  if (n >= N) return;
  int head = lane >> 4;
  int d0 = (lane & 15) * 2;
  unsigned u = Yb[(size_t)n*64 + lane];
  float h0 = bflo(u), h1 = bfhi(u);
  float vs = h0 * asrcw[head*32 + d0] + h1 * asrcw[head*32 + d0 + 1];
  float vd = h0 * adstw[head*32 + d0] + h1 * adstw[head*32 + d0 + 1];
  #pragma unroll
  for (int m = 1; m < 16; m <<= 1){
    vs += __shfl_xor(vs, m, 64);
    vd += __shfl_xor(vd, m, 64);
  }
  if ((lane & 15) == 0){
    a_src[n*4 + head] = vs;
    a_dst[n*4 + head] = vd;
  }
}

// ---------------- GAT aggregation: fused edge weights, 16 lanes/node, 8-deep, perm order, bf16 out ----------------
__global__ __launch_bounds__(256) void k_gat_agg(const uint4* __restrict__ Yb4, const int* __restrict__ csr,
                                                 const int* __restrict__ offs, const int* __restrict__ deg,
                                                 const int* __restrict__ perm,
                                                 const float* __restrict__ asrc, const float* __restrict__ adst,
                                                 const float* __restrict__ bias, u16* __restrict__ outb, int N){
  int gid = blockIdx.x*16 + (threadIdx.x >> 4);
  int l = threadIdx.x & 15;            // 8 channels per lane
  if (gid >= N) return;
  int n = perm[gid];
  int head = l >> 2;
  int beg = offs[n], d = deg[n];
  int dp = (d + 7) & ~7;
  const uint4* cp4 = (const uint4*)(csr + beg);
  float adh = adst[n*4 + head];
  float a[8] = {};
  float sw = 0.f;
  uint4 ia = cp4[0], ib = cp4[1];
  for (int i = 0; i < dp; i += 8){
    int nx = (i + 8 < dp) ? ((i + 8) >> 2) : 0;
    uint4 na = cp4[nx], nb = cp4[nx + 1];
    uint4 v0 = Yb4[(size_t)ia.x*16 + l];
    uint4 v1 = Yb4[(size_t)ia.y*16 + l];
    uint4 v2 = Yb4[(size_t)ia.z*16 + l];
    uint4 v3 = Yb4[(size_t)ia.w*16 + l];
    uint4 v4 = Yb4[(size_t)ib.x*16 + l];
    uint4 v5 = Yb4[(size_t)ib.y*16 + l];
    uint4 v6 = Yb4[(size_t)ib.z*16 + l];
    uint4 v7 = Yb4[(size_t)ib.w*16 + l];
    float e0 = asrc[(size_t)ia.x*4 + head];
    float e1 = asrc[(size_t)ia.y*4 + head];
    float e2 = asrc[(size_t)ia.z*4 + head];
    float e3 = asrc[(size_t)ia.w*4 + head];
    float e4 = asrc[(size_t)ib.x*4 + head];
    float e5 = asrc[(size_t)ib.y*4 + head];
    float e6 = asrc[(size_t)ib.z*4 + head];
    float e7 = asrc[(size_t)ib.w*4 + head];
    float w[8];
    float ee[8] = {e0,e1,e2,e3,e4,e5,e6,e7};
    #pragma unroll
    for (int j = 0; j < 8; ++j){
      float e = ee[j] + adh; e = e > 0.f ? e : 0.2f*e;
      w[j] = __expf(e);
      sw += w[j];
    }
    uint4 vv[8] = {v0,v1,v2,v3,v4,v5,v6,v7};
    #pragma unroll
    for (int j = 0; j < 8; ++j){
      unsigned u0 = vv[j].x, u1 = vv[j].y, u2 = vv[j].z, u3 = vv[j].w;
      float wj = w[j];
      a[0] += wj*bflo(u0); a[1] += wj*bfhi(u0);
      a[2] += wj*bflo(u1); a[3] += wj*bfhi(u1);
      a[4] += wj*bflo(u2); a[5] += wj*bfhi(u2);
      a[6] += wj*bflo(u3); a[7] += wj*bfhi(u3);
    }
    ia = na; ib = nb;
  }
  float inv = 1.f / sw;
  int c0 = l*8;
  float4 b0 = *(const float4*)(bias + c0);
  float4 b1 = *(const float4*)(bias + c0 + 4);
  float bb8[8] = {b0.x,b0.y,b0.z,b0.w,b1.x,b1.y,b1.z,b1.w};
  float og[8];
  #pragma unroll
  for (int c = 0; c < 8; ++c){
    float z = a[c]*inv + bb8[c];
    og[c] = z > 0.f ? z : expm1f(z);
  }
  uint4 o;
  o.x = bfpack2(og[0], og[1]);
  o.y = bfpack2(og[2], og[3]);
  o.z = bfpack2(og[4], og[5]);
  o.w = bfpack2(og[6], og[7]);
  ((uint4*)(outb + (size_t)n*128))[l] = o;
}

// ---------------- GCN aggregation + folded BN + ELU + residual: 8-deep, perm order ----------------
__global__ __launch_bounds__(256) void k_gcn_agg(const uint4* __restrict__ Yb4, const u16* __restrict__ residb,
                                                 u16* __restrict__ outb, float* __restrict__ outf,
                                                 const int* __restrict__ csr,
                                                 const int* __restrict__ offs, const int* __restrict__ deg,
                                                 const int* __restrict__ perm,
                                                 const float* __restrict__ S, const float* __restrict__ T, int N){
  int gid = blockIdx.x*16 + (threadIdx.x >> 4);
  int l = threadIdx.x & 15;
  if (gid >= N) return;
  int n = perm[gid];
  int beg = offs[n], d = deg[n];
  int dp = (d + 7) & ~7;
  const uint4* cp4 = (const uint4*)(csr + beg);
  float a[8] = {};
  uint4 ia = cp4[0], ib = cp4[1];
  for (int i = 0; i < dp; i += 8){
    int nx = (i + 8 < dp) ? ((i + 8) >> 2) : 0;
    uint4 na = cp4[nx], nb = cp4[nx + 1];
    uint4 v0 = Yb4[(size_t)ia.x*16 + l];
    uint4 v1 = Yb4[(size_t)ia.y*16 + l];
    uint4 v2 = Yb4[(size_t)ia.z*16 + l];
    uint4 v3 = Yb4[(size_t)ia.w*16 + l];
    uint4 v4 = Yb4[(size_t)ib.x*16 + l];
    uint4 v5 = Yb4[(size_t)ib.y*16 + l];
    uint4 v6 = Yb4[(size_t)ib.z*16 + l];
    uint4 v7 = Yb4[(size_t)ib.w*16 + l];
    uint4 vv[8] = {v0,v1,v2,v3,v4,v5,v6,v7};
    #pragma unroll
    for (int j = 0; j < 8; ++j){
      unsigned u0 = vv[j].x, u1 = vv[j].y, u2 = vv[j].z, u3 = vv[j].w;
      a[0] += bflo(u0); a[1] += bfhi(u0);
      a[2] += bflo(u1); a[3] += bfhi(u1);
      a[4] += bflo(u2); a[5] += bfhi(u2);
      a[6] += bflo(u3); a[7] += bfhi(u3);
    }
    ia = na; ib = nb;
  }
  float dinv = rsqrtf((float)d);
  int c0 = l*8;
  float4 S0 = *(const float4*)(S + c0), S1 = *(const float4*)(S + c0 + 4);
  float4 T0 = *(const float4*)(T + c0), T1 = *(const float4*)(T + c0 + 4);
  float ss[8] = {S0.x,S0.y,S0.z,S0.w,S1.x,S1.y,S1.z,S1.w};
  float tt[8] = {T0.x,T0.y,T0.z,T0.w,T1.x,T1.y,T1.z,T1.w};
  float rr[8] = {};
  if (residb){
    uint4 r = ((const uint4*)(residb + (size_t)n*128))[l];
    rr[0]=bflo(r.x); rr[1]=bfhi(r.x); rr[2]=bflo(r.y); rr[3]=bfhi(r.y);
    rr[4]=bflo(r.z); rr[5]=bfhi(r.z); rr[6]=bflo(r.w); rr[7]=bfhi(r.w);
  }
  float og[8];
  #pragma unroll
  for (int c = 0; c < 8; ++c){
    float z = a[c]*dinv*ss[c] + tt[c];
    z = z > 0.f ? z : expm1f(z);
    og[c] = z + rr[c];
  }
  if (outb){
    uint4 o;
    o.x = bfpack2(og[0], og[1]);
    o.y = bfpack2(og[2], og[3]);
    o.z = bfpack2(og[4], og[5]);
    o.w = bfpack2(og[6], og[7]);
    ((uint4*)(outb + (size_t)n*128))[l] = o;
  } else {
    float* op = outf + (size_t)n*128 + c0;
    *(float4*)op       = make_float4(og[0],og[1],og[2],og[3]);
    *(float4*)(op + 4) = make_float4(og[4],og[5],og[6],og[7]);
  }
}

// ---------------- mean pool per graph (batch sorted) ----------------
__global__ __launch_bounds__(128) void k_pool(const float* __restrict__ H, const int* __restrict__ batch,
                                              float* __restrict__ G, int N){
  int gid = blockIdx.x; int c = threadIdx.x;
  int lo = 0, hi = N;
  while (lo < hi){ int mid = (lo + hi) >> 1; if (batch[mid] < gid) lo = mid + 1; else hi = mid; }
  int start = lo;
  lo = start; hi = N;
  while (lo < hi){ int mid = (lo + hi) >> 1; if (batch[mid] < gid + 1) lo = mid + 1; else hi = mid; }
  int end = lo;
  float acc = 0.f;
  for (int r = start; r < end; ++r) acc += H[(size_t)r*128 + c];
  float cnt = (float)(end - start);
  G[gid*128 + c] = acc / fmaxf(cnt, 1.0f);
}

// ---------------- MLP head ----------------
__global__ __launch_bounds__(128) void k_mlp(const float* __restrict__ G, const float* __restrict__ p1w,
                                             const float* __restrict__ p1b, const float* __restrict__ p2w,
                                             const float* __restrict__ p2b, const float* __restrict__ cw,
                                             const float* __restrict__ cb, float* __restrict__ out, int NG){
  int gid = blockIdx.x; int t = threadIdx.x;
  __shared__ float gv[128], t1[128], e[64];
  gv[t] = G[gid*128 + t];
  __syncthreads();
  float acc = p1b[t];
  for (int k = 0; k < 128; ++k) acc += gv[k] * p1w[k*128 + t];
  t1[t] = acc > 0.f ? acc : expm1f(acc);
  __syncthreads();
  if (t < 64){
    float a = p2b[t];
    for (int k = 0; k < 128; ++k) a += t1[k] * p2w[k*64 + t];
    e[t] = a;
    out[NG*3 + gid*64 + t] = a;
  }
  __syncthreads();
  if (t < 3){
    float a = cb[t];
    for (int k = 0; k < 64; ++k) a += e[k] * cw[k*3 + t];
    out[gid*3 + t] = a;
  }
}

extern "C" void kernel_launch(void* const* d_in, const int* in_sizes, int n_in,
                              void* d_out, int out_size, void* d_ws, size_t ws_size,
                              hipStream_t stream){
  const float* x      = (const float*)d_in[0];
  const int*   ei     = (const int*)d_in[1];
  const int*   batch  = (const int*)d_in[3];
  const float* gat_w  = (const float*)d_in[4];
  const float* att_s  = (const float*)d_in[5];
  const float* att_d  = (const float*)d_in[6];
  const float* gat_b  = (const float*)d_in[7];
  const float* w1 = (const float*)d_in[8];  const float* b1 = (const float*)d_in[9];
  const float* bn1g = (const float*)d_in[10], *bn1b = (const float*)d_in[11],
             * bn1m = (const float*)d_in[12], *bn1v = (const float*)d_in[13];
  const float* w2 = (const float*)d_in[14]; const float* b2 = (const float*)d_in[15];
  const float* bn2g = (const float*)d_in[16], *bn2b = (const float*)d_in[17],
             * bn2m = (const float*)d_in[18], *bn2v = (const float*)d_in[19];
  const float* w3 = (const float*)d_in[20]; const float* b3 = (const float*)d_in[21];
  const float* bn3g = (const float*)d_in[22], *bn3b = (const float*)d_in[23],
             * bn3m = (const float*)d_in[24], *bn3v = (const float*)d_in[25];
  const float* p1w = (const float*)d_in[26]; const float* p1b = (const float*)d_in[27];
  const float* p2w = (const float*)d_in[28]; const float* p2b = (const float*)d_in[29];
  const float* cw  = (const float*)d_in[30]; const float* cb  = (const float*)d_in[31];

  int N  = in_sizes[3];
  int E  = in_sizes[1] / 2;
  int ET = E + N;
  int NG = out_size / 67;

  char* ws = (char*)d_ws;
  size_t off = 0;
  auto alloc = [&](size_t bytes) -> void* {
    void* p = ws + off;
    off = (off + bytes + 255) & ~(size_t)255;
    return p;
  };
  u16*      Abf  = (u16*)alloc((size_t)N * 128 * 2);         // bf16 layer buffer
  u16*      Bbf  = (u16*)alloc((size_t)N * 128 * 2);         // bf16 layer buffer
  float*    Bact = (float*)alloc((size_t)N * 128 * 4);       // final (pool input) f32
  u16*      Yb   = (u16*)alloc((size_t)(N + 1) * 128 * 2);   // +1 zero pad row
  int*      csr  = (int*)alloc((size_t)(ET + 7*N) * 4);      // padded CSR (8-aligned)
  int*      rank = (int*)alloc((size_t)ET * 4);
  int*      deg  = (int*)alloc((size_t)N * 4);
  int*      offs = (int*)alloc((size_t)N * 4);
  int*      perm = (int*)alloc((size_t)N * 4);
  int*      part = (int*)alloc(1024 * 4);
  int       nb256 = (N + 255) / 256;
  int*      gh   = (int*)alloc((size_t)nb256 * NBUK * 4);
  int*      btot = (int*)alloc(NBUK * 4);
  int*      boff = (int*)alloc(NBUK * 4);
  float*    asrc = (float*)alloc((size_t)(N + 1) * 4 * 4);   // +1 pad row = -1e38
  float*    adst = (float*)alloc((size_t)N * 4 * 4);
  float*    G    = (float*)alloc((size_t)NG * 128 * 4);
  u16*      Wb   = (u16*)alloc(65536 * 2);                   // 4 weight matrices
  float*    bnS  = (float*)alloc(384 * 4);
  float*    bnT  = (float*)alloc(384 * 4);

  hipMemsetAsync(deg,  0, (size_t)N * 4, stream);
  hipMemsetAsync(Yb + (size_t)N*128, 0, 256, stream);        // zero pad row

  int nb = (N + 1023) / 1024;
  int bpp = (ET + 255)/256;
  k_count<<<8*bpp, 256, 0, stream>>>(ei, E, N, deg, rank);
  k_scan_block<<<nb, 1024, 0, stream>>>(deg, offs, part, N);
  k_scan_part<<<1, 1024, 0, stream>>>(part, nb);
  k_hist_blk<<<nb256, 256, 0, stream>>>(deg, gh, N);
  k_colscan<<<NBUK, 1024, 0, stream>>>(gh, btot, nb256);
  k_bucketscan<<<1, NBUK, 0, stream>>>(btot, boff);
  k_finalize<<<nb256, 256, 0, stream>>>(offs, part, deg, csr, boff, gh, perm, N);
  k_fill<<<8*bpp, 256, 0, stream>>>(ei, E, N, offs, rank, csr);

  k_wconv4<<<256, 256, 0, stream>>>(gat_w, w1, w2, w3, Wb);
  k_bnfold<<<1, 384, 0, stream>>>(b1, bn1g, bn1b, bn1m, bn1v,
                                  b2, bn2g, bn2b, bn2m, bn2v,
                                  b3, bn3g, bn3b, bn3m, bn3v, bnS, bnT);

  int gblk = (N + 127) / 128;
  int nblk16 = (N + 15) / 16;
  int ablk = (N + 3) / 4;

  // GAT
  k_gemm_mfma<<<gblk, 256, 0, stream>>>(x, nullptr, Wb, Yb, N, nullptr);
  k_attn<<<ablk, 256, 0, stream>>>((const unsigned*)Yb, att_s, att_d, asrc, adst, N);
  k_gat_agg<<<nblk16, 256, 0, stream>>>((const uint4*)Yb, csr, offs, deg, perm, asrc, adst, gat_b, Abf, N);

  // GCN 1 (residual Abf), out Bbf (bf16)
  k_gemm_mfma<<<gblk, 256, 0, stream>>>(nullptr, Abf, Wb + 16384, Yb, N, deg);
  k_gcn_agg<<<nblk16, 256, 0, stream>>>((const uint4*)Yb, Abf, Bbf, nullptr, csr, offs, deg, perm, bnS, bnT, N);
  // GCN 2 (residual Bbf), out Abf (bf16)
  k_gemm_mfma<<<gblk, 256, 0, stream>>>(nullptr, Bbf, Wb + 32768, Yb, N, deg);
  k_gcn_agg<<<nblk16, 256, 0, stream>>>((const uint4*)Yb, Bbf, Abf, nullptr, csr, offs, deg, perm, bnS + 128, bnT + 128, N);
  // GCN 3 (no residual), out Bact (f32, feeds pool)
  k_gemm_mfma<<<gblk, 256, 0, stream>>>(nullptr, Abf, Wb + 49152, Yb, N, deg);
  k_gcn_agg<<<nblk16, 256, 0, stream>>>((const uint4*)Yb, nullptr, nullptr, Bact, csr, offs, deg, perm, bnS + 256, bnT + 256, N);

  // pool + head
  k_pool<<<NG, 128, 0, stream>>>(Bact, batch, G, N);
  k_mlp<<<NG, 128, 0, stream>>>(G, p1w, p1b, p2w, p2b, cw, cb, (float*)d_out, NG);
}